// Round 9
// baseline (311.518 us; speedup 1.0000x reference)
//
#include <hip/hip_runtime.h>
#include <hip/hip_bf16.h>

#define N 8192
#define FIN 512
#define FOUT 256

typedef __attribute__((ext_vector_type(8))) short bf16x8;
typedef __attribute__((ext_vector_type(4))) float f32x4;

__device__ __forceinline__ unsigned short f2bf(float x) {
  unsigned int u = __float_as_uint(x);
  return (unsigned short)((u + 0x7FFFu + ((u >> 16) & 1u)) >> 16);
}

__device__ __forceinline__ unsigned int pkbf2(float a, float b) {
  __hip_bfloat162 h = __float22bfloat162_rn(make_float2(a, b));
  unsigned int u;
  __builtin_memcpy(&u, &h, 4);
  return u;
}

__device__ __forceinline__ void load_lds16(const void* g, void* l) {
  __builtin_amdgcn_global_load_lds(
      (const __attribute__((address_space(1))) void*)g,
      (__attribute__((address_space(3))) void*)l, 16, 0, 0);
}

// ---------------------------------------------------------------------------
// K1: h = features(8192x512) @ W(512x256), fp32 vector GEMM, 64x64 tile.
// Epilogue also writes hT (bf16, [FOUT][N]) for K4's B-operand staging.
// ---------------------------------------------------------------------------
__global__ __launch_bounds__(256) void gat_k1_gemm_h(
    const float* __restrict__ A, const float* __restrict__ W,
    float* __restrict__ h, unsigned short* __restrict__ hT) {
  __shared__ __align__(16) float As[16][68];
  __shared__ __align__(16) float Bs[16][64];
  const int tid = threadIdx.x;
  const int tx = tid & 15, ty = tid >> 4;
  const int nb = blockIdx.x * 64, mb = blockIdx.y * 64;
  float acc[4][4] = {};
  for (int k0 = 0; k0 < FIN; k0 += 16) {
#pragma unroll
    for (int i = 0; i < 4; ++i) {
      int e = tid + 256 * i;
      int m = e >> 4, k = e & 15;
      As[k][m] = A[(size_t)(mb + m) * FIN + k0 + k];
      int n2 = e & 63, k2 = e >> 6;
      Bs[k2][n2] = W[(size_t)(k0 + k2) * FOUT + nb + n2];
    }
    __syncthreads();
#pragma unroll
    for (int k = 0; k < 16; ++k) {
      float4 av = *reinterpret_cast<const float4*>(&As[k][ty * 4]);
      float4 bv = *reinterpret_cast<const float4*>(&Bs[k][tx * 4]);
      float aa[4] = {av.x, av.y, av.z, av.w};
      float bb[4] = {bv.x, bv.y, bv.z, bv.w};
#pragma unroll
      for (int i = 0; i < 4; ++i)
#pragma unroll
        for (int j = 0; j < 4; ++j) acc[i][j] = fmaf(aa[i], bb[j], acc[i][j]);
    }
    __syncthreads();
  }
#pragma unroll
  for (int i = 0; i < 4; ++i) {
    int m = mb + ty * 4 + i;
#pragma unroll
    for (int j = 0; j < 4; ++j) {
      int n = nb + tx * 4 + j;
      h[(size_t)m * FOUT + n] = acc[i][j];
      hT[(size_t)n * N + m] = f2bf(acc[i][j]);
    }
  }
}

// ---------------------------------------------------------------------------
// K2: hs[i] = h[i,:]@a[:256], hd[i] = h[i,:]@a[256:]. One wave per row.
// ---------------------------------------------------------------------------
__global__ __launch_bounds__(256) void gat_k2_hshd(
    const float* __restrict__ h, const float* __restrict__ a,
    float* __restrict__ hs, float* __restrict__ hd) {
  const int wid = threadIdx.x >> 6;
  const int lane = threadIdx.x & 63;
  const int row = blockIdx.x * 4 + wid;
  float ps = 0.f, pd = 0.f;
#pragma unroll
  for (int i = 0; i < 4; ++i) {
    int c = lane + 64 * i;
    float v = h[(size_t)row * FOUT + c];
    ps += v * a[c];
    pd += v * a[FOUT + c];
  }
#pragma unroll
  for (int off = 32; off >= 1; off >>= 1) {
    ps += __shfl_down(ps, off);
    pd += __shfl_down(pd, off);
  }
  if (lane == 0) {
    hs[row] = ps;
    hd[row] = pd;
  }
}

// ---------------------------------------------------------------------------
// K3 v3: masked softmax rows (no max-subtraction: logits O(+-8), f32-safe,
// validated R4-R8 with identical absmax). One streaming adj pass per row.
// Writes att f32 (required output) AND attB bf16 (if non-null) so K4 reads
// half the bytes with zero conversion work.
// ---------------------------------------------------------------------------
__global__ __launch_bounds__(256) void gat_k3_attn(
    const float* __restrict__ adj, const float* __restrict__ hs,
    const float* __restrict__ hd, float* __restrict__ att,
    unsigned short* __restrict__ attB) {
  __shared__ __align__(16) float hd_s[N];  // 32 KB
  __shared__ float red[4];
  const int tid = threadIdx.x;
  const int lane = tid & 63, wid = tid >> 6;
#pragma unroll
  for (int i = 0; i < 8; ++i) {
    int j = tid * 4 + 1024 * i;
    *reinterpret_cast<float4*>(&hd_s[j]) =
        *reinterpret_cast<const float4*>(&hd[j]);
  }
  __syncthreads();
  const int row0 = blockIdx.x * 8;
  for (int r = 0; r < 8; ++r) {
    const int row = row0 + r;
    const float hsv = hs[row];
    const float* arow = adj + (size_t)row * N;
    float4 l[8];
    float s = 0.f;
#pragma unroll
    for (int i = 0; i < 8; ++i) {
      int j = tid * 4 + 1024 * i;
      float4 a4 = *reinterpret_cast<const float4*>(&arow[j]);
      float4 h4 = *reinterpret_cast<const float4*>(&hd_s[j]);
      float x0 = hsv + h4.x, x1 = hsv + h4.y;
      float x2 = hsv + h4.z, x3 = hsv + h4.w;
      float4 e;
      e.x = (a4.x != 0.f) ? __expf(fmaxf(x0, 0.01f * x0)) : 0.f;
      e.y = (a4.y != 0.f) ? __expf(fmaxf(x1, 0.01f * x1)) : 0.f;
      e.z = (a4.z != 0.f) ? __expf(fmaxf(x2, 0.01f * x2)) : 0.f;
      e.w = (a4.w != 0.f) ? __expf(fmaxf(x3, 0.01f * x3)) : 0.f;
      l[i] = e;
      s += e.x + e.y + e.z + e.w;
    }
#pragma unroll
    for (int off = 32; off >= 1; off >>= 1) s += __shfl_down(s, off);
    if (lane == 0) red[wid] = s;
    __syncthreads();
    s = red[0] + red[1] + red[2] + red[3];
    __syncthreads();
    const float inv = 1.f / s;
    float* orow = att + (size_t)row * N;
    unsigned short* brow = attB ? attB + (size_t)row * N : nullptr;
#pragma unroll
    for (int i = 0; i < 8; ++i) {
      int j = tid * 4 + 1024 * i;
      float4 e = l[i];
      e.x *= inv; e.y *= inv; e.z *= inv; e.w *= inv;
      *reinterpret_cast<float4*>(&orow[j]) = e;
      if (brow) {
        uint2 pk;
        pk.x = pkbf2(e.x, e.y);
        pk.y = pkbf2(e.z, e.w);
        *reinterpret_cast<uint2*>(&brow[j]) = pk;
      }
    }
  }
}

// ---------------------------------------------------------------------------
// K4 v6: out = attB @ h via bf16 MFMA — pure m97-style streaming GEMM.
// BM=32, BN=128, BK=64, 256 threads (4 waves, wave = full-M x 32 cols,
// acc 2x2). Grid = 256 row-blocks x 2 n-halves = 512 blocks; LDS 40 KB ->
// 4 blocks/CU (16 waves/CU; cross-block overlap covers the per-tile vmcnt
// drain -- the occupancy the recompute variants lacked). A and B both staged
// with global_load_lds (ZERO staging VALU), pre-swizzled global source,
// linear LDS dest; XOR-swizzled ds_read (16B-slot ^= row&7). XCD mapping:
// xcd=id&7, nh=xcd>>2 -> each XCD streams one 2 MB L2-resident hT half.
// One barrier per K-step (stage->buf^1 while computing buf).
// BF16A=false fallback (ws too small): A reg-staged from att f32 + cvt.
// ---------------------------------------------------------------------------
template <bool BF16A>
__global__ __launch_bounds__(256, 4) void gat_k4_out(
    const unsigned short* __restrict__ attB, const float* __restrict__ attF,
    const unsigned short* __restrict__ hT, float* __restrict__ C) {
  __shared__ __align__(16) unsigned short As[2][32 * 64];   // 2 x 4 KB
  __shared__ __align__(16) unsigned short Bs[2][128 * 64];  // 2 x 16 KB
  const int tid = threadIdx.x;
  const int lane = tid & 63;
  const int wn = tid >> 6;  // wave 0..3 -> 32-col slice
  const int g = lane >> 4, rsel = lane & 15;
  const int id = blockIdx.x;
  const int xcd = id & 7, j = id >> 3;
  const int nh = xcd >> 2;
  const int row0 = ((xcd & 3) + 4 * j) * 32;
  const int nb0 = nh * 128;

  // A staging (bf16 path): 256 slots, 1/thread: r=s>>3, sl=s&7
  const unsigned short* asrcB = nullptr;
  int aofsB = 0;
  // A staging (f32 path): 512 f32x4 slots, 2/thread
  const float* asrcF[2] = {nullptr, nullptr};
  int awF[2] = {0, 0};
  if (BF16A) {
    int r = tid >> 3, sl = tid & 7;
    asrcB = attB + (size_t)(row0 + r) * N + (sl ^ (r & 7)) * 8;
    aofsB = tid * 16;
  } else {
#pragma unroll
    for (int i = 0; i < 2; ++i) {
      int e = tid + 256 * i;
      int r = e >> 4, p = e & 15;
      asrcF[i] = attF + (size_t)(row0 + r) * N + p * 4;
      awF[i] = r * 128 + ((((p >> 1) ^ (r & 7)) << 4)) + (p & 1) * 8;
    }
  }
  // B staging: 1024 slots, 4/thread: n=s>>3, sl=s&7, pre-swizzled source
  const unsigned short* bsrc[4];
  int bofs[4];
#pragma unroll
  for (int i = 0; i < 4; ++i) {
    int s = tid + 256 * i;
    int n = s >> 3, sl = s & 7;
    bsrc[i] = hT + (size_t)(nb0 + n) * N + (sl ^ (n & 7)) * 8;
    bofs[i] = s * 16;
  }

  f32x4 acc[2][2] = {};
  float4 aF0, aF1;

  // prologue: stage tile 0 into buf 0
  if (BF16A) {
    load_lds16(asrcB, reinterpret_cast<char*>(As[0]) + aofsB);
  } else {
    aF0 = *reinterpret_cast<const float4*>(asrcF[0]);
    aF1 = *reinterpret_cast<const float4*>(asrcF[1]);
    uint2 pk;
    pk.x = pkbf2(aF0.x, aF0.y); pk.y = pkbf2(aF0.z, aF0.w);
    *reinterpret_cast<uint2*>(reinterpret_cast<char*>(As[0]) + awF[0]) = pk;
    pk.x = pkbf2(aF1.x, aF1.y); pk.y = pkbf2(aF1.z, aF1.w);
    *reinterpret_cast<uint2*>(reinterpret_cast<char*>(As[0]) + awF[1]) = pk;
  }
#pragma unroll
  for (int i = 0; i < 4; ++i)
    load_lds16(bsrc[i], reinterpret_cast<char*>(Bs[0]) + bofs[i]);
  __syncthreads();

  int cur = 0;
  for (int t = 0; t < 128; ++t) {
    // issue next tile's staging first (latency hidden under MFMA + other blocks)
    if (t < 127) {
      const int kel = (t + 1) * 64;
      if (BF16A) {
        load_lds16(asrcB + kel, reinterpret_cast<char*>(As[cur ^ 1]) + aofsB);
      } else {
        aF0 = *reinterpret_cast<const float4*>(asrcF[0] + kel);
        aF1 = *reinterpret_cast<const float4*>(asrcF[1] + kel);
      }
#pragma unroll
      for (int i = 0; i < 4; ++i)
        load_lds16(bsrc[i] + kel, reinterpret_cast<char*>(Bs[cur ^ 1]) + bofs[i]);
    }
    // MFMA current tile
    const char* Ac = reinterpret_cast<const char*>(As[cur]);
    const char* Bc = reinterpret_cast<const char*>(Bs[cur]);
#pragma unroll
    for (int ks = 0; ks < 2; ++ks) {
      bf16x8 af[2], bg[2];
#pragma unroll
      for (int i = 0; i < 2; ++i) {
        int rr = i * 16 + rsel;
        af[i] = *reinterpret_cast<const bf16x8*>(
            Ac + rr * 128 + (((ks * 4 + g) ^ (rr & 7)) << 4));
        int n = wn * 32 + i * 16 + rsel;
        bg[i] = *reinterpret_cast<const bf16x8*>(
            Bc + n * 128 + (((ks * 4 + g) ^ (n & 7)) << 4));
      }
#pragma unroll
      for (int i = 0; i < 2; ++i)
#pragma unroll
        for (int f = 0; f < 2; ++f)
          acc[i][f] = __builtin_amdgcn_mfma_f32_16x16x32_bf16(af[i], bg[f],
                                                              acc[i][f], 0, 0, 0);
    }
    // f32 path: convert + ds_write next A after MFMA
    if (!BF16A && t < 127) {
      char* An = reinterpret_cast<char*>(As[cur ^ 1]);
      uint2 pk;
      pk.x = pkbf2(aF0.x, aF0.y); pk.y = pkbf2(aF0.z, aF0.w);
      *reinterpret_cast<uint2*>(An + awF[0]) = pk;
      pk.x = pkbf2(aF1.x, aF1.y); pk.y = pkbf2(aF1.z, aF1.w);
      *reinterpret_cast<uint2*>(An + awF[1]) = pk;
    }
    __syncthreads();  // drains staging; buf ready
    if (t < 127) cur ^= 1;
  }
  // C store: C/D layout col=lane&15, row=(lane>>4)*4+reg
#pragma unroll
  for (int i = 0; i < 2; ++i)
#pragma unroll
    for (int f = 0; f < 2; ++f)
#pragma unroll
      for (int r = 0; r < 4; ++r) {
        int row = row0 + i * 16 + g * 4 + r;
        int col = nb0 + wn * 32 + f * 16 + rsel;
        C[(size_t)row * FOUT + col] = acc[i][f][r];
      }
}

extern "C" void kernel_launch(void* const* d_in, const int* in_sizes, int n_in,
                              void* d_out, int out_size, void* d_ws, size_t ws_size,
                              hipStream_t stream) {
  const float* features = (const float*)d_in[0];
  const float* adj = (const float*)d_in[1];
  const float* W = (const float*)d_in[2];
  const float* a = (const float*)d_in[3];

  float* out = (float*)d_out;           // [N][FOUT]
  float* att = out + (size_t)N * FOUT;  // [N][N]

  char* ws = (char*)d_ws;
  float* h = (float*)ws;                                         // 8 MB
  unsigned short* hT = (unsigned short*)(ws + (size_t)8388608);  // 4 MB
  float* hs = (float*)(ws + (size_t)12582912);
  float* hd = hs + N;
  unsigned short* attB = (unsigned short*)(ws + (size_t)16777216);  // 134 MB
  const size_t need = 16777216 + (size_t)N * N * 2;
  const bool useB = ws_size >= need;

  hipLaunchKernelGGL(gat_k1_gemm_h, dim3(FOUT / 64, N / 64), dim3(256), 0,
                     stream, features, W, h, hT);
  hipLaunchKernelGGL(gat_k2_hshd, dim3(N / 4), dim3(256), 0, stream, h, a, hs,
                     hd);
  hipLaunchKernelGGL(gat_k3_attn, dim3(N / 8), dim3(256), 0, stream, adj, hs,
                     hd, att, useB ? attB : nullptr);
  if (useB)
    hipLaunchKernelGGL(gat_k4_out<true>, dim3(512), dim3(256), 0, stream,
                       attB, att, hT, out);
  else
    hipLaunchKernelGGL(gat_k4_out<false>, dim3(512), dim3(256), 0, stream,
                       attB, att, hT, out);
}

// Round 10
// 264.283 us; speedup vs baseline: 1.1787x; 1.1787x over previous
//
#include <hip/hip_runtime.h>
#include <hip/hip_bf16.h>

#define N 8192
#define FIN 512
#define FOUT 256

typedef __attribute__((ext_vector_type(8))) short bf16x8;
typedef __attribute__((ext_vector_type(4))) float f32x4;

__device__ __forceinline__ unsigned short f2bf(float x) {
  unsigned int u = __float_as_uint(x);
  return (unsigned short)((u + 0x7FFFu + ((u >> 16) & 1u)) >> 16);
}

__device__ __forceinline__ unsigned int pkbf2(float a, float b) {
  __hip_bfloat162 h = __float22bfloat162_rn(make_float2(a, b));
  unsigned int u;
  __builtin_memcpy(&u, &h, 4);
  return u;
}

__device__ __forceinline__ void load_lds16(const void* g, void* l) {
  __builtin_amdgcn_global_load_lds(
      (const __attribute__((address_space(1))) void*)g,
      (__attribute__((address_space(3))) void*)l, 16, 0, 0);
}

// ---------------------------------------------------------------------------
// K1: h = features(8192x512) @ W(512x256), fp32 vector GEMM, 64x64 tile.
// Epilogue also writes hT (bf16, [FOUT][N]) for K4's B-operand staging.
// ---------------------------------------------------------------------------
__global__ __launch_bounds__(256) void gat_k1_gemm_h(
    const float* __restrict__ A, const float* __restrict__ W,
    float* __restrict__ h, unsigned short* __restrict__ hT) {
  __shared__ __align__(16) float As[16][68];
  __shared__ __align__(16) float Bs[16][64];
  const int tid = threadIdx.x;
  const int tx = tid & 15, ty = tid >> 4;
  const int nb = blockIdx.x * 64, mb = blockIdx.y * 64;
  float acc[4][4] = {};
  for (int k0 = 0; k0 < FIN; k0 += 16) {
#pragma unroll
    for (int i = 0; i < 4; ++i) {
      int e = tid + 256 * i;
      int m = e >> 4, k = e & 15;
      As[k][m] = A[(size_t)(mb + m) * FIN + k0 + k];
      int n2 = e & 63, k2 = e >> 6;
      Bs[k2][n2] = W[(size_t)(k0 + k2) * FOUT + nb + n2];
    }
    __syncthreads();
#pragma unroll
    for (int k = 0; k < 16; ++k) {
      float4 av = *reinterpret_cast<const float4*>(&As[k][ty * 4]);
      float4 bv = *reinterpret_cast<const float4*>(&Bs[k][tx * 4]);
      float aa[4] = {av.x, av.y, av.z, av.w};
      float bb[4] = {bv.x, bv.y, bv.z, bv.w};
#pragma unroll
      for (int i = 0; i < 4; ++i)
#pragma unroll
        for (int j = 0; j < 4; ++j) acc[i][j] = fmaf(aa[i], bb[j], acc[i][j]);
    }
    __syncthreads();
  }
#pragma unroll
  for (int i = 0; i < 4; ++i) {
    int m = mb + ty * 4 + i;
#pragma unroll
    for (int j = 0; j < 4; ++j) {
      int n = nb + tx * 4 + j;
      h[(size_t)m * FOUT + n] = acc[i][j];
      hT[(size_t)n * N + m] = f2bf(acc[i][j]);
    }
  }
}

// ---------------------------------------------------------------------------
// K2: hs[i] = h[i,:]@a[:256], hd[i] = h[i,:]@a[256:]. One wave per row.
// Also zero-fills `out` (8 MB) for K4's split-K atomics.
// ---------------------------------------------------------------------------
__global__ __launch_bounds__(256) void gat_k2_hshd(
    const float* __restrict__ h, const float* __restrict__ a,
    float* __restrict__ hs, float* __restrict__ hd, float* __restrict__ out) {
  const int gid = blockIdx.x * 256 + threadIdx.x;
  *reinterpret_cast<float4*>(out + (size_t)gid * 4) =
      make_float4(0.f, 0.f, 0.f, 0.f);

  const int wid = threadIdx.x >> 6;
  const int lane = threadIdx.x & 63;
  const int row = blockIdx.x * 4 + wid;
  float ps = 0.f, pd = 0.f;
#pragma unroll
  for (int i = 0; i < 4; ++i) {
    int c = lane + 64 * i;
    float v = h[(size_t)row * FOUT + c];
    ps += v * a[c];
    pd += v * a[FOUT + c];
  }
#pragma unroll
  for (int off = 32; off >= 1; off >>= 1) {
    ps += __shfl_down(ps, off);
    pd += __shfl_down(pd, off);
  }
  if (lane == 0) {
    hs[row] = ps;
    hd[row] = pd;
  }
}

// ---------------------------------------------------------------------------
// K3 v3: masked softmax rows (no max-subtraction: logits O(+-8), f32-safe,
// validated R4-R9 with identical absmax). One streaming adj pass per row.
// Writes att f32 (required output) AND attB bf16 (if non-null) so K4 reads
// half the bytes with zero conversion work.
// ---------------------------------------------------------------------------
__global__ __launch_bounds__(256) void gat_k3_attn(
    const float* __restrict__ adj, const float* __restrict__ hs,
    const float* __restrict__ hd, float* __restrict__ att,
    unsigned short* __restrict__ attB) {
  __shared__ __align__(16) float hd_s[N];  // 32 KB
  __shared__ float red[4];
  const int tid = threadIdx.x;
  const int lane = tid & 63, wid = tid >> 6;
#pragma unroll
  for (int i = 0; i < 8; ++i) {
    int j = tid * 4 + 1024 * i;
    *reinterpret_cast<float4*>(&hd_s[j]) =
        *reinterpret_cast<const float4*>(&hd[j]);
  }
  __syncthreads();
  const int row0 = blockIdx.x * 8;
  for (int r = 0; r < 8; ++r) {
    const int row = row0 + r;
    const float hsv = hs[row];
    const float* arow = adj + (size_t)row * N;
    float4 l[8];
    float s = 0.f;
#pragma unroll
    for (int i = 0; i < 8; ++i) {
      int j = tid * 4 + 1024 * i;
      float4 a4 = *reinterpret_cast<const float4*>(&arow[j]);
      float4 h4 = *reinterpret_cast<const float4*>(&hd_s[j]);
      float x0 = hsv + h4.x, x1 = hsv + h4.y;
      float x2 = hsv + h4.z, x3 = hsv + h4.w;
      float4 e;
      e.x = (a4.x != 0.f) ? __expf(fmaxf(x0, 0.01f * x0)) : 0.f;
      e.y = (a4.y != 0.f) ? __expf(fmaxf(x1, 0.01f * x1)) : 0.f;
      e.z = (a4.z != 0.f) ? __expf(fmaxf(x2, 0.01f * x2)) : 0.f;
      e.w = (a4.w != 0.f) ? __expf(fmaxf(x3, 0.01f * x3)) : 0.f;
      l[i] = e;
      s += e.x + e.y + e.z + e.w;
    }
#pragma unroll
    for (int off = 32; off >= 1; off >>= 1) s += __shfl_down(s, off);
    if (lane == 0) red[wid] = s;
    __syncthreads();
    s = red[0] + red[1] + red[2] + red[3];
    __syncthreads();
    const float inv = 1.f / s;
    float* orow = att + (size_t)row * N;
    unsigned short* brow = attB ? attB + (size_t)row * N : nullptr;
#pragma unroll
    for (int i = 0; i < 8; ++i) {
      int j = tid * 4 + 1024 * i;
      float4 e = l[i];
      e.x *= inv; e.y *= inv; e.z *= inv; e.w *= inv;
      *reinterpret_cast<float4*>(&orow[j]) = e;
      if (brow) {
        uint2 pk;
        pk.x = pkbf2(e.x, e.y);
        pk.y = pkbf2(e.z, e.w);
        *reinterpret_cast<uint2*>(&brow[j]) = pk;
      }
    }
  }
}

// ---------------------------------------------------------------------------
// K4 v7: out = attB @ h via bf16 MFMA with the m201 counted-vmcnt pipeline.
// BM=64, BN=128, BK=64, K-split=2 -> grid = 128 rowblk x 2 nh x 2 kq = 512
// blocks of 512 threads (8 waves, wave tile 32x32, acc 2x2). LDS = 3 bufs x
// (8KB A + 16KB B) = 72 KB -> 2 blocks/CU. Staging via global_load_lds
// (pre-swizzled source, linear dest; read with matching XOR swizzle),
// issued TWO phases ahead into buf[(t+2)%3]; per phase:
//   s_waitcnt vmcnt(3)  [stage(t) landed; t+1,t+2 stay in flight -- never 0]
//   s_barrier + sched_barrier
//   STAGE(t+2)          [after barrier: prior reader of that buf was
//                        MFMA(t-1), separated by this barrier]
//   8 MFMAs from buf[t%3]
// XCD pinning: xcd=id&7 -> (nh, kq, row-half); per-XCD hT panel = 1 MB,
// L2-resident. Split-K partials via f32 atomicAdd (out zeroed by K2).
// ---------------------------------------------------------------------------
__global__ __launch_bounds__(512, 4) void gat_k4_out(
    const unsigned short* __restrict__ attB,
    const unsigned short* __restrict__ hT, float* __restrict__ C) {
  __shared__ __align__(16) unsigned short Asb[3 * 64 * 64];   // 24 KB
  __shared__ __align__(16) unsigned short Bsb[3 * 128 * 64];  // 48 KB
  const int tid = threadIdx.x;
  const int lane = tid & 63;
  const int wid = tid >> 6;
  const int wm = wid & 1, wn = wid >> 1;  // 2M x 4N waves, tile 32x32
  const int g = lane >> 4, rsel = lane & 15;
  const int id = blockIdx.x;
  const int xcd = id & 7, pos = id >> 3;  // pos 0..63
  const int nh = xcd & 1, kq = (xcd >> 1) & 1, rh = xcd >> 2;
  const int row0 = (rh * 64 + pos) * 64;
  const int nb0 = nh * 128;
  const size_t kbase = (size_t)kq * 4096;

  // A staging: 512 slots (64 rows x 8 kgroups), 1/thread
  const int ara = tid >> 3, asl = tid & 7;
  const unsigned short* asrc =
      attB + (size_t)(row0 + ara) * N + kbase + (asl ^ (ara & 7)) * 8;
  const int aofs = tid * 16;
  // B staging: 1024 slots (128 n x 8 kgroups), 2/thread
  const unsigned short* bsrc[2];
  int bofs[2];
#pragma unroll
  for (int i = 0; i < 2; ++i) {
    int s = tid + 512 * i;
    int n = s >> 3, sl = s & 7;
    bsrc[i] = hT + (size_t)(nb0 + n) * N + kbase + (sl ^ (n & 7)) * 8;
    bofs[i] = s * 16;
  }

#define STAGE(T, BUF)                                                        \
  do {                                                                       \
    const int kel = (T) * 64;                                                \
    char* Ad = reinterpret_cast<char*>(Asb) + (BUF) * 8192;                  \
    char* Bd = reinterpret_cast<char*>(Bsb) + (BUF) * 16384;                 \
    load_lds16(asrc + kel, Ad + aofs);                                       \
    load_lds16(bsrc[0] + kel, Bd + bofs[0]);                                 \
    load_lds16(bsrc[1] + kel, Bd + bofs[1]);                                 \
  } while (0)

  f32x4 acc[2][2] = {};

  // prologue: 2 tiles in flight
  STAGE(0, 0);
  STAGE(1, 1);

  int cur = 0, stg = 2;
  for (int t = 0; t < 64; ++t) {
    if (t < 63)
      asm volatile("s_waitcnt vmcnt(3)" ::: "memory");  // stage(t) landed
    else
      asm volatile("s_waitcnt vmcnt(0)" ::: "memory");
    __builtin_amdgcn_s_barrier();
    __builtin_amdgcn_sched_barrier(0);
    if (t < 62) STAGE(t + 2, stg);
    const char* Ac = reinterpret_cast<const char*>(Asb) + cur * 8192;
    const char* Bc = reinterpret_cast<const char*>(Bsb) + cur * 16384;
#pragma unroll
    for (int ks = 0; ks < 2; ++ks) {
      const int kg = ks * 4 + g;
      bf16x8 af[2], bg[2];
#pragma unroll
      for (int i = 0; i < 2; ++i) {
        int rr = wm * 32 + i * 16 + rsel;
        af[i] = *reinterpret_cast<const bf16x8*>(
            Ac + rr * 128 + ((kg ^ (rr & 7)) << 4));
        int n = wn * 32 + i * 16 + rsel;
        bg[i] = *reinterpret_cast<const bf16x8*>(
            Bc + n * 128 + ((kg ^ (n & 7)) << 4));
      }
#pragma unroll
      for (int i = 0; i < 2; ++i)
#pragma unroll
        for (int f = 0; f < 2; ++f)
          acc[i][f] = __builtin_amdgcn_mfma_f32_16x16x32_bf16(af[i], bg[f],
                                                              acc[i][f], 0, 0, 0);
    }
    cur = (cur == 2) ? 0 : cur + 1;
    stg = (stg == 2) ? 0 : stg + 1;
  }
#undef STAGE
  // split-K accumulate: C/D layout col=lane&15, row=(lane>>4)*4+reg
#pragma unroll
  for (int i = 0; i < 2; ++i)
#pragma unroll
    for (int f = 0; f < 2; ++f)
#pragma unroll
      for (int r = 0; r < 4; ++r) {
        int row = row0 + wm * 32 + i * 16 + g * 4 + r;
        int col = nb0 + wn * 32 + f * 16 + rsel;
        atomicAdd(&C[(size_t)row * FOUT + col], acc[i][f][r]);
      }
}

// ---------------------------------------------------------------------------
// K4 fallback (ws too small for attB): R9's f32-A reg-staged variant.
// BM=32, BN=128, direct store (no split-K).
// ---------------------------------------------------------------------------
__global__ __launch_bounds__(256, 4) void gat_k4_fb(
    const float* __restrict__ attF, const unsigned short* __restrict__ hT,
    float* __restrict__ C) {
  __shared__ __align__(16) unsigned short As[2][32 * 64];
  __shared__ __align__(16) unsigned short Bs[2][128 * 64];
  const int tid = threadIdx.x;
  const int lane = tid & 63;
  const int wn = tid >> 6;
  const int g = lane >> 4, rsel = lane & 15;
  const int id = blockIdx.x;
  const int xcd = id & 7, j = id >> 3;
  const int nh = xcd >> 2;
  const int row0 = ((xcd & 3) + 4 * j) * 32;
  const int nb0 = nh * 128;

  const float* asrcF[2];
  int awF[2];
#pragma unroll
  for (int i = 0; i < 2; ++i) {
    int e = tid + 256 * i;
    int r = e >> 4, p = e & 15;
    asrcF[i] = attF + (size_t)(row0 + r) * N + p * 4;
    awF[i] = r * 128 + ((((p >> 1) ^ (r & 7)) << 4)) + (p & 1) * 8;
  }
  const unsigned short* bsrc[4];
  int bofs[4];
#pragma unroll
  for (int i = 0; i < 4; ++i) {
    int s = tid + 256 * i;
    int n = s >> 3, sl = s & 7;
    bsrc[i] = hT + (size_t)(nb0 + n) * N + (sl ^ (n & 7)) * 8;
    bofs[i] = s * 16;
  }

  f32x4 acc[2][2] = {};
  float4 aF0, aF1;
  aF0 = *reinterpret_cast<const float4*>(asrcF[0]);
  aF1 = *reinterpret_cast<const float4*>(asrcF[1]);
  {
    uint2 pk;
    pk.x = pkbf2(aF0.x, aF0.y); pk.y = pkbf2(aF0.z, aF0.w);
    *reinterpret_cast<uint2*>(reinterpret_cast<char*>(As[0]) + awF[0]) = pk;
    pk.x = pkbf2(aF1.x, aF1.y); pk.y = pkbf2(aF1.z, aF1.w);
    *reinterpret_cast<uint2*>(reinterpret_cast<char*>(As[0]) + awF[1]) = pk;
  }
#pragma unroll
  for (int i = 0; i < 4; ++i)
    load_lds16(bsrc[i], reinterpret_cast<char*>(Bs[0]) + bofs[i]);
  __syncthreads();

  int cur = 0;
  for (int t = 0; t < 128; ++t) {
    if (t < 127) {
      const int kel = (t + 1) * 64;
      aF0 = *reinterpret_cast<const float4*>(asrcF[0] + kel);
      aF1 = *reinterpret_cast<const float4*>(asrcF[1] + kel);
#pragma unroll
      for (int i = 0; i < 4; ++i)
        load_lds16(bsrc[i] + kel, reinterpret_cast<char*>(Bs[cur ^ 1]) + bofs[i]);
    }
    const char* Ac = reinterpret_cast<const char*>(As[cur]);
    const char* Bc = reinterpret_cast<const char*>(Bs[cur]);
#pragma unroll
    for (int ks = 0; ks < 2; ++ks) {
      bf16x8 af[2], bg[2];
#pragma unroll
      for (int i = 0; i < 2; ++i) {
        int rr = i * 16 + rsel;
        af[i] = *reinterpret_cast<const bf16x8*>(
            Ac + rr * 128 + (((ks * 4 + g) ^ (rr & 7)) << 4));
        int n = wn * 32 + i * 16 + rsel;
        bg[i] = *reinterpret_cast<const bf16x8*>(
            Bc + n * 128 + (((ks * 4 + g) ^ (n & 7)) << 4));
      }
#pragma unroll
      for (int i = 0; i < 2; ++i)
#pragma unroll
        for (int f = 0; f < 2; ++f)
          acc[i][f] = __builtin_amdgcn_mfma_f32_16x16x32_bf16(af[i], bg[f],
                                                              acc[i][f], 0, 0, 0);
    }
    if (t < 127) {
      char* An = reinterpret_cast<char*>(As[cur ^ 1]);
      uint2 pk;
      pk.x = pkbf2(aF0.x, aF0.y); pk.y = pkbf2(aF0.z, aF0.w);
      *reinterpret_cast<uint2*>(An + awF[0]) = pk;
      pk.x = pkbf2(aF1.x, aF1.y); pk.y = pkbf2(aF1.z, aF1.w);
      *reinterpret_cast<uint2*>(An + awF[1]) = pk;
    }
    __syncthreads();
    if (t < 127) cur ^= 1;
  }
#pragma unroll
  for (int i = 0; i < 2; ++i)
#pragma unroll
    for (int f = 0; f < 2; ++f)
#pragma unroll
      for (int r = 0; r < 4; ++r) {
        int row = row0 + i * 16 + g * 4 + r;
        int col = nb0 + wn * 32 + f * 16 + rsel;
        C[(size_t)row * FOUT + col] = acc[i][f][r];
      }
}

extern "C" void kernel_launch(void* const* d_in, const int* in_sizes, int n_in,
                              void* d_out, int out_size, void* d_ws, size_t ws_size,
                              hipStream_t stream) {
  const float* features = (const float*)d_in[0];
  const float* adj = (const float*)d_in[1];
  const float* W = (const float*)d_in[2];
  const float* a = (const float*)d_in[3];

  float* out = (float*)d_out;           // [N][FOUT]
  float* att = out + (size_t)N * FOUT;  // [N][N]

  char* ws = (char*)d_ws;
  float* h = (float*)ws;                                         // 8 MB
  unsigned short* hT = (unsigned short*)(ws + (size_t)8388608);  // 4 MB
  float* hs = (float*)(ws + (size_t)12582912);
  float* hd = hs + N;
  unsigned short* attB = (unsigned short*)(ws + (size_t)16777216);  // 134 MB
  const size_t need = 16777216 + (size_t)N * N * 2;
  const bool useB = ws_size >= need;

  hipLaunchKernelGGL(gat_k1_gemm_h, dim3(FOUT / 64, N / 64), dim3(256), 0,
                     stream, features, W, h, hT);
  hipLaunchKernelGGL(gat_k2_hshd, dim3(N / 4), dim3(256), 0, stream, h, a, hs,
                     hd, out);
  hipLaunchKernelGGL(gat_k3_attn, dim3(N / 8), dim3(256), 0, stream, adj, hs,
                     hd, att, useB ? attB : nullptr);
  if (useB)
    hipLaunchKernelGGL(gat_k4_out, dim3(512), dim3(512), 0, stream, attB, hT,
                       out);
  else
    hipLaunchKernelGGL(gat_k4_fb, dim3(512), dim3(256), 0, stream, att, hT,
                       out);
}

// Round 11
// 254.875 us; speedup vs baseline: 1.2222x; 1.0369x over previous
//
#include <hip/hip_runtime.h>
#include <hip/hip_bf16.h>

#define N 8192
#define FIN 512
#define FOUT 256

typedef __attribute__((ext_vector_type(8))) short bf16x8;
typedef __attribute__((ext_vector_type(4))) float f32x4;

__device__ __forceinline__ unsigned short f2bf(float x) {
  unsigned int u = __float_as_uint(x);
  return (unsigned short)((u + 0x7FFFu + ((u >> 16) & 1u)) >> 16);
}

__device__ __forceinline__ unsigned int pkbf2(float a, float b) {
  __hip_bfloat162 h = __float22bfloat162_rn(make_float2(a, b));
  unsigned int u;
  __builtin_memcpy(&u, &h, 4);
  return u;
}

__device__ __forceinline__ void load_lds16(const void* g, void* l) {
  __builtin_amdgcn_global_load_lds(
      (const __attribute__((address_space(1))) void*)g,
      (__attribute__((address_space(3))) void*)l, 16, 0, 0);
}

// ---------------------------------------------------------------------------
// K1: h = features(8192x512) @ W(512x256), fp32 vector GEMM, 64x64 tile.
// Epilogue also writes hT (bf16, [FOUT][N]) for K4's B-operand staging.
// ---------------------------------------------------------------------------
__global__ __launch_bounds__(256) void gat_k1_gemm_h(
    const float* __restrict__ A, const float* __restrict__ W,
    float* __restrict__ h, unsigned short* __restrict__ hT) {
  __shared__ __align__(16) float As[16][68];
  __shared__ __align__(16) float Bs[16][64];
  const int tid = threadIdx.x;
  const int tx = tid & 15, ty = tid >> 4;
  const int nb = blockIdx.x * 64, mb = blockIdx.y * 64;
  float acc[4][4] = {};
  for (int k0 = 0; k0 < FIN; k0 += 16) {
#pragma unroll
    for (int i = 0; i < 4; ++i) {
      int e = tid + 256 * i;
      int m = e >> 4, k = e & 15;
      As[k][m] = A[(size_t)(mb + m) * FIN + k0 + k];
      int n2 = e & 63, k2 = e >> 6;
      Bs[k2][n2] = W[(size_t)(k0 + k2) * FOUT + nb + n2];
    }
    __syncthreads();
#pragma unroll
    for (int k = 0; k < 16; ++k) {
      float4 av = *reinterpret_cast<const float4*>(&As[k][ty * 4]);
      float4 bv = *reinterpret_cast<const float4*>(&Bs[k][tx * 4]);
      float aa[4] = {av.x, av.y, av.z, av.w};
      float bb[4] = {bv.x, bv.y, bv.z, bv.w};
#pragma unroll
      for (int i = 0; i < 4; ++i)
#pragma unroll
        for (int j = 0; j < 4; ++j) acc[i][j] = fmaf(aa[i], bb[j], acc[i][j]);
    }
    __syncthreads();
  }
#pragma unroll
  for (int i = 0; i < 4; ++i) {
    int m = mb + ty * 4 + i;
#pragma unroll
    for (int j = 0; j < 4; ++j) {
      int n = nb + tx * 4 + j;
      h[(size_t)m * FOUT + n] = acc[i][j];
      hT[(size_t)n * N + m] = f2bf(acc[i][j]);
    }
  }
}

// ---------------------------------------------------------------------------
// K2: hs[i] = h[i,:]@a[:256], hd[i] = h[i,:]@a[256:]. One wave per row.
// ---------------------------------------------------------------------------
__global__ __launch_bounds__(256) void gat_k2_hshd(
    const float* __restrict__ h, const float* __restrict__ a,
    float* __restrict__ hs, float* __restrict__ hd) {
  const int wid = threadIdx.x >> 6;
  const int lane = threadIdx.x & 63;
  const int row = blockIdx.x * 4 + wid;
  float ps = 0.f, pd = 0.f;
#pragma unroll
  for (int i = 0; i < 4; ++i) {
    int c = lane + 64 * i;
    float v = h[(size_t)row * FOUT + c];
    ps += v * a[c];
    pd += v * a[FOUT + c];
  }
#pragma unroll
  for (int off = 32; off >= 1; off >>= 1) {
    ps += __shfl_down(ps, off);
    pd += __shfl_down(pd, off);
  }
  if (lane == 0) {
    hs[row] = ps;
    hd[row] = pd;
  }
}

// ---------------------------------------------------------------------------
// K3 v3: masked softmax rows (no max-subtraction: logits O(+-8), f32-safe,
// validated R4-R10 with identical absmax). One streaming adj pass per row.
// Writes att f32 (required output) AND attB bf16 (if non-null; L3-resident
// 134 MB) so K4 reads half the bytes with zero conversion work.
// ---------------------------------------------------------------------------
__global__ __launch_bounds__(256) void gat_k3_attn(
    const float* __restrict__ adj, const float* __restrict__ hs,
    const float* __restrict__ hd, float* __restrict__ att,
    unsigned short* __restrict__ attB) {
  __shared__ __align__(16) float hd_s[N];  // 32 KB
  __shared__ float red[4];
  const int tid = threadIdx.x;
  const int lane = tid & 63, wid = tid >> 6;
#pragma unroll
  for (int i = 0; i < 8; ++i) {
    int j = tid * 4 + 1024 * i;
    *reinterpret_cast<float4*>(&hd_s[j]) =
        *reinterpret_cast<const float4*>(&hd[j]);
  }
  __syncthreads();
  const int row0 = blockIdx.x * 8;
  for (int r = 0; r < 8; ++r) {
    const int row = row0 + r;
    const float hsv = hs[row];
    const float* arow = adj + (size_t)row * N;
    float4 l[8];
    float s = 0.f;
#pragma unroll
    for (int i = 0; i < 8; ++i) {
      int j = tid * 4 + 1024 * i;
      float4 a4 = *reinterpret_cast<const float4*>(&arow[j]);
      float4 h4 = *reinterpret_cast<const float4*>(&hd_s[j]);
      float x0 = hsv + h4.x, x1 = hsv + h4.y;
      float x2 = hsv + h4.z, x3 = hsv + h4.w;
      float4 e;
      e.x = (a4.x != 0.f) ? __expf(fmaxf(x0, 0.01f * x0)) : 0.f;
      e.y = (a4.y != 0.f) ? __expf(fmaxf(x1, 0.01f * x1)) : 0.f;
      e.z = (a4.z != 0.f) ? __expf(fmaxf(x2, 0.01f * x2)) : 0.f;
      e.w = (a4.w != 0.f) ? __expf(fmaxf(x3, 0.01f * x3)) : 0.f;
      l[i] = e;
      s += e.x + e.y + e.z + e.w;
    }
#pragma unroll
    for (int off = 32; off >= 1; off >>= 1) s += __shfl_down(s, off);
    if (lane == 0) red[wid] = s;
    __syncthreads();
    s = red[0] + red[1] + red[2] + red[3];
    __syncthreads();
    const float inv = 1.f / s;
    float* orow = att + (size_t)row * N;
    unsigned short* brow = attB ? attB + (size_t)row * N : nullptr;
#pragma unroll
    for (int i = 0; i < 8; ++i) {
      int j = tid * 4 + 1024 * i;
      float4 e = l[i];
      e.x *= inv; e.y *= inv; e.z *= inv; e.w *= inv;
      *reinterpret_cast<float4*>(&orow[j]) = e;
      if (brow) {
        uint2 pk;
        pk.x = pkbf2(e.x, e.y);
        pk.y = pkbf2(e.z, e.w);
        *reinterpret_cast<uint2*>(&brow[j]) = pk;
      }
    }
  }
}

// ---------------------------------------------------------------------------
// K4 v8: part_kq = attB_slice @ h_slice via bf16 MFMA 16x16x32.
// Fix targeted this round: LDS-read amplification. acc[4][2] (wave tile
// 64x32) -> 12 ds_read_b128 feed 16 MFMAs per phase (0.75 reads/MFMA vs 1.0
// in all prior K4s). BM=128, BN=128, BK=64, Ksplit=4 -> grid = 64 rb x 2 nh
// x 4 kq = 512 blocks of 512 thr (8 waves 2Mx4N), LDS 64 KB -> 2 blocks/CU.
// Both operands staged via global_load_lds (zero staging VALU), pre-swizzled
// source, linear dest, XOR-swizzled read ((slot^(row&7))<<4 -- conflict-free
// for the 16-row fragment pattern). Phase order (T3-minimum): STAGE(t+1)
// FIRST, then MFMA(t) covers the drain, then one __syncthreads.
// Race-safe: stage(t+2) is issued only after barrier(t+1). No atomics --
// partials written to ws, reduced by K5.
// XCD pinning: xcd=id&7 -> (nh,kq); per-XCD hT panel 512 KB, L2-resident.
// ---------------------------------------------------------------------------
__global__ __launch_bounds__(512, 4) void gat_k4_out(
    const unsigned short* __restrict__ attB,
    const unsigned short* __restrict__ hT, float* __restrict__ part) {
  __shared__ __align__(16) unsigned short As[2][128 * 64];  // 2 x 16 KB
  __shared__ __align__(16) unsigned short Bs[2][128 * 64];  // 2 x 16 KB
  const int tid = threadIdx.x;
  const int lane = tid & 63;
  const int wid = tid >> 6;               // 0..7
  const int wm = wid >> 2, wn = wid & 3;  // 2M x 4N, wave tile 64x32
  const int g = lane >> 4, rsel = lane & 15;
  const int id = blockIdx.x;
  const int xcd = id & 7;
  const int nh = xcd & 1, kq = xcd >> 1;  // kq 0..3 pinned per XCD-pair
  const int rb = id >> 3;                 // 0..63
  const int row0 = rb * 128;
  const int nb0 = nh * 128;
  const size_t kbase = (size_t)kq * 2048;

  // A staging: 1024 slots (128 rows x 8 kgroups), 2/thread
  const unsigned short* asrc[2];
  int aofs[2];
#pragma unroll
  for (int i = 0; i < 2; ++i) {
    int s = tid + 512 * i;
    int r = s >> 3, sl = s & 7;
    asrc[i] = attB + (size_t)(row0 + r) * N + kbase + (sl ^ (r & 7)) * 8;
    aofs[i] = s * 16;
  }
  // B staging: 1024 slots (128 n x 8 kgroups), 2/thread
  const unsigned short* bsrc[2];
  int bofs[2];
#pragma unroll
  for (int i = 0; i < 2; ++i) {
    int s = tid + 512 * i;
    int n = s >> 3, sl = s & 7;
    bsrc[i] = hT + (size_t)(nb0 + n) * N + kbase + (sl ^ (n & 7)) * 8;
    bofs[i] = s * 16;
  }

#define STAGE(T, BUF)                                           \
  do {                                                          \
    const int kel = (T) * 64;                                   \
    char* Ad = reinterpret_cast<char*>(As[(BUF)]);              \
    char* Bd = reinterpret_cast<char*>(Bs[(BUF)]);              \
    load_lds16(asrc[0] + kel, Ad + aofs[0]);                    \
    load_lds16(asrc[1] + kel, Ad + aofs[1]);                    \
    load_lds16(bsrc[0] + kel, Bd + bofs[0]);                    \
    load_lds16(bsrc[1] + kel, Bd + bofs[1]);                    \
  } while (0)

  f32x4 acc[4][2] = {};

  STAGE(0, 0);
  __syncthreads();

  int cur = 0;
  for (int t = 0; t < 32; ++t) {
    // 1. issue next tile's staging FIRST (MFMA below covers the latency;
    //    target buf cur^1 was last read at phase t-1, sealed by barrier(t-1))
    if (t < 31) STAGE(t + 1, cur ^ 1);
    // 2. MFMA current tile: 12 ds_read_b128 -> 16 MFMAs per ks-pair
    const char* Ac = reinterpret_cast<const char*>(As[cur]);
    const char* Bc = reinterpret_cast<const char*>(Bs[cur]);
#pragma unroll
    for (int ks = 0; ks < 2; ++ks) {
      const int kg = ks * 4 + g;
      bf16x8 af[4], bg[2];
#pragma unroll
      for (int i = 0; i < 4; ++i) {
        int rr = wm * 64 + i * 16 + rsel;
        af[i] = *reinterpret_cast<const bf16x8*>(
            Ac + rr * 128 + ((kg ^ (rr & 7)) << 4));
      }
#pragma unroll
      for (int j = 0; j < 2; ++j) {
        int n = wn * 32 + j * 16 + rsel;
        bg[j] = *reinterpret_cast<const bf16x8*>(
            Bc + n * 128 + ((kg ^ (n & 7)) << 4));
      }
#pragma unroll
      for (int i = 0; i < 4; ++i)
#pragma unroll
        for (int j = 0; j < 2; ++j)
          acc[i][j] = __builtin_amdgcn_mfma_f32_16x16x32_bf16(af[i], bg[j],
                                                              acc[i][j], 0, 0, 0);
    }
    // 3. one barrier: drains stage(t+1) (covered) + seals reads of cur
    __syncthreads();
    cur ^= 1;
  }
#undef STAGE
  // partial store (no atomics): C/D layout col=lane&15, row=(lane>>4)*4+reg
  float* pq = part + (size_t)kq * N * FOUT;
#pragma unroll
  for (int i = 0; i < 4; ++i)
#pragma unroll
    for (int j = 0; j < 2; ++j)
#pragma unroll
      for (int r = 0; r < 4; ++r) {
        int row = row0 + wm * 64 + i * 16 + g * 4 + r;
        int col = nb0 + wn * 32 + j * 16 + rsel;
        pq[(size_t)row * FOUT + col] = acc[i][j][r];
      }
}

// ---------------------------------------------------------------------------
// K5: out = sum of 4 split-K partials. 32 MB read + 8 MB write.
// ---------------------------------------------------------------------------
__global__ __launch_bounds__(256) void gat_k5_red(
    const float* __restrict__ part, float* __restrict__ out) {
  const size_t i = ((size_t)blockIdx.x * 256 + threadIdx.x) * 4;
  const size_t S = (size_t)N * FOUT;
  float4 s0 = *reinterpret_cast<const float4*>(part + i);
  float4 s1 = *reinterpret_cast<const float4*>(part + S + i);
  float4 s2 = *reinterpret_cast<const float4*>(part + 2 * S + i);
  float4 s3 = *reinterpret_cast<const float4*>(part + 3 * S + i);
  float4 r;
  r.x = (s0.x + s1.x) + (s2.x + s3.x);
  r.y = (s0.y + s1.y) + (s2.y + s3.y);
  r.z = (s0.z + s1.z) + (s2.z + s3.z);
  r.w = (s0.w + s1.w) + (s2.w + s3.w);
  *reinterpret_cast<float4*>(out + i) = r;
}

// ---------------------------------------------------------------------------
// K4 fallback (ws too small for attB+part): f32-A reg-staged direct-store.
// ---------------------------------------------------------------------------
__global__ __launch_bounds__(256, 4) void gat_k4_fb(
    const float* __restrict__ attF, const unsigned short* __restrict__ hT,
    float* __restrict__ C) {
  __shared__ __align__(16) unsigned short As[2][32 * 64];
  __shared__ __align__(16) unsigned short Bs[2][128 * 64];
  const int tid = threadIdx.x;
  const int lane = tid & 63;
  const int wn = tid >> 6;
  const int g = lane >> 4, rsel = lane & 15;
  const int id = blockIdx.x;
  const int xcd = id & 7, j = id >> 3;
  const int nh = xcd >> 2;
  const int row0 = ((xcd & 3) + 4 * j) * 32;
  const int nb0 = nh * 128;

  const float* asrcF[2];
  int awF[2];
#pragma unroll
  for (int i = 0; i < 2; ++i) {
    int e = tid + 256 * i;
    int r = e >> 4, p = e & 15;
    asrcF[i] = attF + (size_t)(row0 + r) * N + p * 4;
    awF[i] = r * 128 + ((((p >> 1) ^ (r & 7)) << 4)) + (p & 1) * 8;
  }
  const unsigned short* bsrc[4];
  int bofs[4];
#pragma unroll
  for (int i = 0; i < 4; ++i) {
    int s = tid + 256 * i;
    int n = s >> 3, sl = s & 7;
    bsrc[i] = hT + (size_t)(nb0 + n) * N + (sl ^ (n & 7)) * 8;
    bofs[i] = s * 16;
  }

  f32x4 acc[2][2] = {};
  float4 aF0, aF1;
  aF0 = *reinterpret_cast<const float4*>(asrcF[0]);
  aF1 = *reinterpret_cast<const float4*>(asrcF[1]);
  {
    uint2 pk;
    pk.x = pkbf2(aF0.x, aF0.y); pk.y = pkbf2(aF0.z, aF0.w);
    *reinterpret_cast<uint2*>(reinterpret_cast<char*>(As[0]) + awF[0]) = pk;
    pk.x = pkbf2(aF1.x, aF1.y); pk.y = pkbf2(aF1.z, aF1.w);
    *reinterpret_cast<uint2*>(reinterpret_cast<char*>(As[0]) + awF[1]) = pk;
  }
#pragma unroll
  for (int i = 0; i < 4; ++i)
    load_lds16(bsrc[i], reinterpret_cast<char*>(Bs[0]) + bofs[i]);
  __syncthreads();

  int cur = 0;
  for (int t = 0; t < 128; ++t) {
    if (t < 127) {
      const int kel = (t + 1) * 64;
      aF0 = *reinterpret_cast<const float4*>(asrcF[0] + kel);
      aF1 = *reinterpret_cast<const float4*>(asrcF[1] + kel);
#pragma unroll
      for (int i = 0; i < 4; ++i)
        load_lds16(bsrc[i] + kel, reinterpret_cast<char*>(Bs[cur ^ 1]) + bofs[i]);
    }
    const char* Ac = reinterpret_cast<const char*>(As[cur]);
    const char* Bc = reinterpret_cast<const char*>(Bs[cur]);
#pragma unroll
    for (int ks = 0; ks < 2; ++ks) {
      bf16x8 af[2], bg[2];
#pragma unroll
      for (int i = 0; i < 2; ++i) {
        int rr = i * 16 + rsel;
        af[i] = *reinterpret_cast<const bf16x8*>(
            Ac + rr * 128 + (((ks * 4 + g) ^ (rr & 7)) << 4));
        int n = wn * 32 + i * 16 + rsel;
        bg[i] = *reinterpret_cast<const bf16x8*>(
            Bc + n * 128 + (((ks * 4 + g) ^ (n & 7)) << 4));
      }
#pragma unroll
      for (int i = 0; i < 2; ++i)
#pragma unroll
        for (int f = 0; f < 2; ++f)
          acc[i][f] = __builtin_amdgcn_mfma_f32_16x16x32_bf16(af[i], bg[f],
                                                              acc[i][f], 0, 0, 0);
    }
    if (t < 127) {
      char* An = reinterpret_cast<char*>(As[cur ^ 1]);
      uint2 pk;
      pk.x = pkbf2(aF0.x, aF0.y); pk.y = pkbf2(aF0.z, aF0.w);
      *reinterpret_cast<uint2*>(An + awF[0]) = pk;
      pk.x = pkbf2(aF1.x, aF1.y); pk.y = pkbf2(aF1.z, aF1.w);
      *reinterpret_cast<uint2*>(An + awF[1]) = pk;
    }
    __syncthreads();
    if (t < 127) cur ^= 1;
  }
#pragma unroll
  for (int i = 0; i < 2; ++i)
#pragma unroll
    for (int f = 0; f < 2; ++f)
#pragma unroll
      for (int r = 0; r < 4; ++r) {
        int row = row0 + i * 16 + g * 4 + r;
        int col = nb0 + wn * 32 + f * 16 + rsel;
        C[(size_t)row * FOUT + col] = acc[i][f][r];
      }
}

extern "C" void kernel_launch(void* const* d_in, const int* in_sizes, int n_in,
                              void* d_out, int out_size, void* d_ws, size_t ws_size,
                              hipStream_t stream) {
  const float* features = (const float*)d_in[0];
  const float* adj = (const float*)d_in[1];
  const float* W = (const float*)d_in[2];
  const float* a = (const float*)d_in[3];

  float* out = (float*)d_out;           // [N][FOUT]
  float* att = out + (size_t)N * FOUT;  // [N][N]

  char* ws = (char*)d_ws;
  float* h = (float*)ws;                                         // 8 MB
  unsigned short* hT = (unsigned short*)(ws + (size_t)8388608);  // 4 MB
  float* hs = (float*)(ws + (size_t)12582912);
  float* hd = hs + N;
  unsigned short* attB = (unsigned short*)(ws + (size_t)16777216);  // 134 MB
  float* part = (float*)(ws + (size_t)16777216 + (size_t)N * N * 2);  // 32 MB
  const size_t need =
      16777216 + (size_t)N * N * 2 + (size_t)4 * N * FOUT * 4;
  const bool useB = ws_size >= need;

  hipLaunchKernelGGL(gat_k1_gemm_h, dim3(FOUT / 64, N / 64), dim3(256), 0,
                     stream, features, W, h, hT);
  hipLaunchKernelGGL(gat_k2_hshd, dim3(N / 4), dim3(256), 0, stream, h, a, hs,
                     hd);
  hipLaunchKernelGGL(gat_k3_attn, dim3(N / 8), dim3(256), 0, stream, adj, hs,
                     hd, att, useB ? attB : nullptr);
  if (useB) {
    hipLaunchKernelGGL(gat_k4_out, dim3(512), dim3(512), 0, stream, attB, hT,
                       part);
    hipLaunchKernelGGL(gat_k5_red, dim3(N * FOUT / 1024), dim3(256), 0, stream,
                       part, out);
  } else {
    hipLaunchKernelGGL(gat_k4_fb, dim3(512), dim3(256), 0, stream, att, hT,
                       out);
  }
}